// Round 9
// baseline (1814.212 us; speedup 1.0000x reference)
//
#include <hip/hip_runtime.h>
#include <math.h>

// PLRNN forward via MFMA matvec, 4-wave op-minimal variant.
// 256 batches x 1024 steps, 1 WG (256 thr, 4 waves) per batch, 1 per CU.
// Cost law (R1-R7 fit): step ~= 12cy x LDS-wave-ops. 4 waves halve broadcast
// redundancy: bz 16 + bounce 32 + br 64+4 + misc ~= 130 ops (R4: 206).
// Weights resident as f16 MFMA fragments (~256 VGPR/thread; gfx950 allows
// ~512 VGPR/wave at 1 wave/SIMD, launch_bounds(256,1)).
// Per step (2 barriers):
//   p1 (M-split): wave w -> pre rows [128w,128w+128): 8mt x 4kt = 32 MFMA.
//   bounce (masked r15==0): relu+f16 -> rt[128w..128w+128), 8 ops.  B0.
//   p2 (M-split): wave w -> u rows [32w,32w+32): 2mt x 16kt = 32 MFMA + 2
//       tail MFMA (k=512..543: [C|0] x [s~|0]); 16 br reads + 1 brt.
//   update on D-lanes: znew = A*zf + u + h1; TF (waves 0-1); publish zf_h;
//       wave 3 stages s~(t+1). B2.
// X/S/out staged in LDS per 128-step chunk -> no global ops in steady state.

#define NB 256
#define T  1024
#define DX 64
#define DZ 128
#define DH 512
#define DS 16
#define CHUNK 128

typedef _Float16 half8 __attribute__((ext_vector_type(8)));
typedef _Float16 v4h   __attribute__((ext_vector_type(4)));
typedef float    f32x4 __attribute__((ext_vector_type(4)));

__device__ __forceinline__ half8 cvt8(const float* __restrict__ src) {
  const float4 a = *reinterpret_cast<const float4*>(src);
  const float4 c = *reinterpret_cast<const float4*>(src + 4);
  half8 h;
  h[0] = (_Float16)a.x; h[1] = (_Float16)a.y; h[2] = (_Float16)a.z; h[3] = (_Float16)a.w;
  h[4] = (_Float16)c.x; h[5] = (_Float16)c.y; h[6] = (_Float16)c.z; h[7] = (_Float16)c.w;
  return h;
}

__global__ __launch_bounds__(256, 1) void plrnn_kernel(
    const float* __restrict__ X, const float* __restrict__ S,
    const float* __restrict__ A, const float* __restrict__ W1,
    const float* __restrict__ W2, const float* __restrict__ h1,
    const float* __restrict__ h2, const float* __restrict__ C,
    float* __restrict__ out)
{
  __shared__ __align__(16) _Float16 zf_h[DZ];          // 256 B
  __shared__ __align__(16) _Float16 rt[544];           // r(512) + s~(16) + pad(16)
  __shared__ __align__(16) float    Xc[CHUNK][DX];     // 32 KiB: X[t+1 .. t+128]
  __shared__ __align__(16) float    Sc[CHUNK][DS];     // 8 KiB:  S[t .. t+127]
  __shared__ __align__(16) float    outc[CHUNK][DX];   // 32 KiB

  const int b   = blockIdx.x;
  const int tid = threadIdx.x;
  const int w   = tid >> 6;            // wave 0..3
  const int l   = tid & 63;
  const int g   = l >> 4;              // 16-lane group (B k-slice / D row-block)
  const int r15 = l & 15;              // A row-in-tile / D col

  // ---- one-time: stage chunk 0 (X rows 1..128 clamped, S rows 0..127) ----
  {
    #pragma unroll
    for (int k = 0; k < 8; ++k) {
      const int flat = k * 1024 + tid * 4;
      int srow = 1 + (flat >> 6);
      if (srow > T - 1) srow = T - 1;
      const float4 v = *reinterpret_cast<const float4*>(X + ((size_t)b * T + srow) * DX + (flat & 63));
      *reinterpret_cast<float4*>(&((float*)Xc)[flat]) = v;
    }
    #pragma unroll
    for (int k = 0; k < 2; ++k) {
      const int flat = k * 1024 + tid * 4;
      const float4 v = *reinterpret_cast<const float4*>(S + ((size_t)b * T) * DS + flat);
      *reinterpret_cast<float4*>(&((float*)Sc)[flat]) = v;
    }
  }

  // ---- one-time: s~(0) + pad ----
  if (tid < 16) {
    rt[512 + tid] = (_Float16)S[((size_t)b * T) * DS + tid];
    rt[528 + tid] = (_Float16)0.0f;
  }

  // ---- one-time: W2 A-fragments (wave w: rows 128w+16mt+r15, k=32kt+8g+e) ----
  half8 w2f[8][4];
  #pragma unroll
  for (int mt = 0; mt < 8; ++mt)
    #pragma unroll
    for (int kt = 0; kt < 4; ++kt)
      w2f[mt][kt] = cvt8(W2 + ((size_t)b * DH + 128 * w + 16 * mt + r15) * DZ + 32 * kt + 8 * g);

  // ---- one-time: W1 A-fragments (rows 32w+16mt+r15, k=32kt+8g+e) ----
  half8 w1f[2][16];
  #pragma unroll
  for (int mt = 0; mt < 2; ++mt)
    #pragma unroll
    for (int kt = 0; kt < 16; ++kt)
      w1f[mt][kt] = cvt8(W1 + ((size_t)b * DZ + 32 * w + 16 * mt + r15) * DH + 32 * kt + 8 * g);

  // ---- one-time: tail fragments (C cols, k=512+8g+e for g<2; else 0) ----
  half8 w1ft[2];
  #pragma unroll
  for (int mt = 0; mt < 2; ++mt) {
    #pragma unroll
    for (int e = 0; e < 8; ++e) w1ft[mt][e] = (_Float16)0.0f;
    const int row = 32 * w + 16 * mt + r15;
    if (g == 0)      w1ft[mt] = cvt8(C + ((size_t)b * DZ + row) * DS + 0);
    else if (g == 1) w1ft[mt] = cvt8(C + ((size_t)b * DZ + row) * DS + 8);
  }

  // ---- one-time: h2 as acc-init (D rows 4g+j of each mt) ----
  f32x4 h2v[8];
  #pragma unroll
  for (int mt = 0; mt < 8; ++mt)
    h2v[mt] = *reinterpret_cast<const f32x4*>(h2 + (size_t)b * DH + 128 * w + 16 * mt + 4 * g);

  // ---- one-time: update constants (rows 32w+16mt+4g+j on r15==0 lanes) ----
  f32x4 Areg[2], h1reg[2], zfcur[2];
  #pragma unroll
  for (int mt = 0; mt < 2; ++mt) {
    Areg[mt] = (f32x4){0.f, 0.f, 0.f, 0.f};
    h1reg[mt] = (f32x4){0.f, 0.f, 0.f, 0.f};
    zfcur[mt] = (f32x4){0.f, 0.f, 0.f, 0.f};
  }
  if (r15 == 0) {
    #pragma unroll
    for (int mt = 0; mt < 2; ++mt) {
      const int row = 32 * w + 16 * mt + 4 * g;
      Areg[mt]  = *reinterpret_cast<const f32x4*>(A  + (size_t)b * DZ + row);
      h1reg[mt] = *reinterpret_cast<const f32x4*>(h1 + (size_t)b * DZ + row);
      if (row < DX) {
        const f32x4 x0 = *reinterpret_cast<const f32x4*>(X + ((size_t)b * T) * DX + row);
        #pragma unroll
        for (int j = 0; j < 4; ++j) zfcur[mt][j] = (x0[j] != x0[j]) ? 0.f : x0[j];  // zf(0)
      }
      v4h zp;
      #pragma unroll
      for (int j = 0; j < 4; ++j) zp[j] = (_Float16)zfcur[mt][j];
      *reinterpret_cast<v4h*>(&zf_h[row]) = zp;
    }
  }
  __syncthreads();

  const f32x4 zero4 = {0.f, 0.f, 0.f, 0.f};

  for (int t = 0; t < T; ++t) {
    // ---- chunk boundary: flush out-chunk, stage next X/S chunk + s~ ----
    if ((t & (CHUNK - 1)) == 0 && t) {
      const int c0 = t - CHUNK;
      #pragma unroll
      for (int k = 0; k < 8; ++k) {
        const int flat = k * 1024 + tid * 4;
        const float4 v = *reinterpret_cast<const float4*>(&((float*)outc)[flat]);
        *reinterpret_cast<float4*>(out + ((size_t)b * T + c0) * DX + flat) = v;
      }
      #pragma unroll
      for (int k = 0; k < 8; ++k) {
        const int flat = k * 1024 + tid * 4;
        int srow = t + 1 + (flat >> 6);
        if (srow > T - 1) srow = T - 1;
        const float4 v = *reinterpret_cast<const float4*>(X + ((size_t)b * T + srow) * DX + (flat & 63));
        *reinterpret_cast<float4*>(&((float*)Xc)[flat]) = v;
      }
      #pragma unroll
      for (int k = 0; k < 2; ++k) {
        const int flat = k * 1024 + tid * 4;
        const float4 v = *reinterpret_cast<const float4*>(S + ((size_t)b * T + t) * DS + flat);
        *reinterpret_cast<float4*>(&((float*)Sc)[flat]) = v;
      }
      if (tid < 16) rt[512 + tid] = (_Float16)S[((size_t)b * T + t) * DS + tid];
      __syncthreads();
    }
    const int tc = t & (CHUNK - 1);

    // ---- phase 1: pre = h2 + W2·zf (32 MFMA, 8 chains of depth 4) ----
    half8 bz[4];
    #pragma unroll
    for (int kt = 0; kt < 4; ++kt)
      bz[kt] = *reinterpret_cast<const half8*>(zf_h + 32 * kt + 8 * g);

    f32x4 acc1[8];
    #pragma unroll
    for (int mt = 0; mt < 8; ++mt)
      acc1[mt] = __builtin_amdgcn_mfma_f32_16x16x32_f16(w2f[mt][0], bz[0], h2v[mt], 0, 0, 0);
    #pragma unroll
    for (int kt = 1; kt < 4; ++kt)
      #pragma unroll
      for (int mt = 0; mt < 8; ++mt)
        acc1[mt] = __builtin_amdgcn_mfma_f32_16x16x32_f16(w2f[mt][kt], bz[kt], acc1[mt], 0, 0, 0);

    // ---- bounce (masked r15==0): relu+f16 -> rt[128w..128w+128), 8 ops ----
    if (r15 == 0) {
      #pragma unroll
      for (int mt = 0; mt < 8; ++mt) {
        v4h p;
        p[0] = (_Float16)fmaxf(acc1[mt][0], 0.f);
        p[1] = (_Float16)fmaxf(acc1[mt][1], 0.f);
        p[2] = (_Float16)fmaxf(acc1[mt][2], 0.f);
        p[3] = (_Float16)fmaxf(acc1[mt][3], 0.f);
        *reinterpret_cast<v4h*>(&rt[128 * w + 16 * mt + 4 * g]) = p;
      }
    }
    __syncthreads();   // B0: rt complete

    // ---- phase 2: u rows [32w,32w+32): 2mt x 16kt + 2 tail (34 MFMA) ----
    const half8 brt = *reinterpret_cast<const half8*>(rt + 512 + 8 * g);
    f32x4 a0[4], a1[4];   // 4 chains per mt, depth 4
    a0[0] = __builtin_amdgcn_mfma_f32_16x16x32_f16(w1ft[0], brt, zero4, 0, 0, 0);
    a1[0] = __builtin_amdgcn_mfma_f32_16x16x32_f16(w1ft[1], brt, zero4, 0, 0, 0);
    #pragma unroll
    for (int c = 1; c < 4; ++c) { a0[c] = zero4; a1[c] = zero4; }
    #pragma unroll
    for (int kt = 0; kt < 16; ++kt) {
      const half8 br = *reinterpret_cast<const half8*>(rt + 32 * kt + 8 * g);
      a0[kt & 3] = __builtin_amdgcn_mfma_f32_16x16x32_f16(w1f[0][kt], br, a0[kt & 3], 0, 0, 0);
      a1[kt & 3] = __builtin_amdgcn_mfma_f32_16x16x32_f16(w1f[1][kt], br, a1[kt & 3], 0, 0, 0);
    }

    // ---- distributed update on D-lanes (rows 32w+16mt+4g..+4) ----
    if (r15 == 0) {
      f32x4 u[2];
      u[0] = (a0[0] + a0[1]) + (a0[2] + a0[3]);
      u[1] = (a1[0] + a1[1]) + (a1[2] + a1[3]);
      #pragma unroll
      for (int mt = 0; mt < 2; ++mt) {
        const int row = 32 * w + 16 * mt + 4 * g;
        f32x4 zn, zfn;
        #pragma unroll
        for (int j = 0; j < 4; ++j) zn[j] = Areg[mt][j] * zfcur[mt][j] + u[mt][j] + h1reg[mt][j];
        zfn = zn;
        if (row < DX) {
          *reinterpret_cast<f32x4*>(&outc[tc][row]) = zn;
          const f32x4 xv = *reinterpret_cast<const f32x4*>(&Xc[tc][row]);
          #pragma unroll
          for (int j = 0; j < 4; ++j)
            zfn[j] = (xv[j] != xv[j]) ? zn[j] : (0.125f * xv[j] + 0.875f * zn[j]);
        }
        zfcur[mt] = zfn;
        v4h zp;
        #pragma unroll
        for (int j = 0; j < 4; ++j) zp[j] = (_Float16)zfn[j];
        *reinterpret_cast<v4h*>(&zf_h[row]) = zp;
      }
    }
    // ---- stage s~(t+1) (wave 3; skipped at chunk boundary) ----
    if (w == 3 && l < 4 && ((t + 1) & (CHUNK - 1)) != 0) {
      const f32x4 sv = *reinterpret_cast<const f32x4*>(&Sc[(t + 1) & (CHUNK - 1)][4 * l]);
      v4h sp;
      #pragma unroll
      for (int j = 0; j < 4; ++j) sp[j] = (_Float16)sv[j];
      *reinterpret_cast<v4h*>(&rt[512 + 4 * l]) = sp;
    }
    __syncthreads();   // B2: zf(t+1) + s~(t+1) visible
  }

  // ---- final flush (last chunk) ----
  {
    const int c0 = T - CHUNK;
    #pragma unroll
    for (int k = 0; k < 8; ++k) {
      const int flat = k * 1024 + tid * 4;
      const float4 v = *reinterpret_cast<const float4*>(&((float*)outc)[flat]);
      *reinterpret_cast<float4*>(out + ((size_t)b * T + c0) * DX + flat) = v;
    }
  }
}

extern "C" void kernel_launch(void* const* d_in, const int* in_sizes, int n_in,
                              void* d_out, int out_size, void* d_ws, size_t ws_size,
                              hipStream_t stream) {
  const float* X  = (const float*)d_in[0];
  const float* S  = (const float*)d_in[1];
  const float* A  = (const float*)d_in[2];
  const float* W1 = (const float*)d_in[3];
  const float* W2 = (const float*)d_in[4];
  const float* h1 = (const float*)d_in[5];
  const float* h2 = (const float*)d_in[6];
  const float* C  = (const float*)d_in[7];
  float* out = (float*)d_out;
  plrnn_kernel<<<dim3(NB), dim3(256), 0, stream>>>(X, S, A, W1, W2, h1, h2, C, out);
}

// Round 10
// 1130.061 us; speedup vs baseline: 1.6054x; 1.6054x over previous
//
#include <hip/hip_runtime.h>
#include <math.h>

// PLRNN forward via MFMA matvec. 256 batches x 1024 steps, 1 WG (512 thr,
// 8 waves) per batch, 1 per CU. Weights resident as f16 MFMA fragments.
// LDS-op-minimal schedule (cost law: step ~= 12cy x per-CU LDS wave-ops):
//   p1 (M-split): wave w -> pre rows [64w,64w+64): 4x4 MFMA, C-in = h2.
//       Results column-replicated (B broadcast) -> ALL lanes hold pre.
//   bounce: column-spread single op: lane r15<4 writes relu(pre) rows
//       16*r15+4g (sel tree, static cndmask) -> rt[64w..64w+64).
//   p2 (K-split): wave w -> partials u[0..127] over k in [64w,64w+64):
//       8mt x 2kt MFMA reading ONLY own bounce rows (wave-local, no barrier);
//       per-wave tail MFMA (C.s~ for rows [16w,16w+16)) folded via mt==w.
//   pwrite: column-spread: each lane writes 2 f32 partials to part[z][w]
//       (stride 9 -> writes <=4-way, reads <=2-way).  B1.
//   reduce: lane reads part[row0][c4], part[row0][4+c4] (row0=16w+(l>>2));
//       2 DPP quad-perm xor-adds -> u(row0) in every lane.
//   update: zn = A*zf + u + h1 (all f32, per-lane state); TF via Xc;
//       c4==0 lanes publish zf_h (b16) + outc; wave 7 stages s~(t+1). B2.
// X/S/out staged in LDS per 128-step chunk -> no global ops in steady state.

#define NB 256
#define T  1024
#define DX 64
#define DZ 128
#define DH 512
#define DS 16
#define CHUNK 128

typedef _Float16 half8 __attribute__((ext_vector_type(8)));
typedef _Float16 v4h   __attribute__((ext_vector_type(4)));
typedef float    f32x4 __attribute__((ext_vector_type(4)));

__device__ __forceinline__ half8 cvt8(const float* __restrict__ src) {
  const float4 a = *reinterpret_cast<const float4*>(src);
  const float4 c = *reinterpret_cast<const float4*>(src + 4);
  half8 h;
  h[0] = (_Float16)a.x; h[1] = (_Float16)a.y; h[2] = (_Float16)a.z; h[3] = (_Float16)a.w;
  h[4] = (_Float16)c.x; h[5] = (_Float16)c.y; h[6] = (_Float16)c.z; h[7] = (_Float16)c.w;
  return h;
}

__device__ __forceinline__ f32x4 sel4(int c, f32x4 a, f32x4 b) {   // c ? a : b
  f32x4 r;
  r[0] = c ? a[0] : b[0];  r[1] = c ? a[1] : b[1];
  r[2] = c ? a[2] : b[2];  r[3] = c ? a[3] : b[3];
  return r;
}

template <int CTRL>
__device__ __forceinline__ float dpp_xor_add(float v) {   // v + v[lane^d] (in-quad)
  const int t = __builtin_amdgcn_update_dpp(0, __float_as_int(v), CTRL, 0xF, 0xF, true);
  return v + __int_as_float(t);
}

__global__ __launch_bounds__(512, 2) void plrnn_kernel(
    const float* __restrict__ X, const float* __restrict__ S,
    const float* __restrict__ A, const float* __restrict__ W1,
    const float* __restrict__ W2, const float* __restrict__ h1,
    const float* __restrict__ h2, const float* __restrict__ C,
    float* __restrict__ out)
{
  __shared__ __align__(16) _Float16 zf_h[DZ];          // 256 B
  __shared__ __align__(16) _Float16 rt[544];           // r(512) + s~(16) + zeroed(16)
  __shared__ __align__(16) float    part[DZ][9];       // 4.5 KiB, odd stride
  __shared__ __align__(16) float    Xc[CHUNK][DX];     // 32 KiB: X[t+1 .. t+128]
  __shared__ __align__(16) float    Sc[CHUNK][DS];     // 8 KiB:  S[t .. t+127]
  __shared__ __align__(16) float    outc[CHUNK][DX];   // 32 KiB

  const int b    = blockIdx.x;
  const int tid  = threadIdx.x;
  const int w    = tid >> 6;           // wave 0..7
  const int l    = tid & 63;
  const int g    = l >> 4;             // 16-lane group (B k-slice / D row-block)
  const int r15  = l & 15;             // A row-in-tile / D col
  const int c4   = l & 3;              // quad lane (= partial index in reduce)
  const int k16  = l >> 2;             // 0..15
  const int row0 = 16 * w + k16;       // this lane's state row (dup x4)

  // ---- one-time: stage chunk 0 (X rows 1..128 clamped, S rows 0..127) ----
  {
    #pragma unroll
    for (int k = 0; k < 4; ++k) {
      const int flat = k * 2048 + tid * 4;
      int srow = 1 + (flat >> 6);
      if (srow > T - 1) srow = T - 1;
      const float4 v = *reinterpret_cast<const float4*>(X + ((size_t)b * T + srow) * DX + (flat & 63));
      *reinterpret_cast<float4*>(&((float*)Xc)[flat]) = v;
    }
    const int flat = tid * 4;
    const float4 v = *reinterpret_cast<const float4*>(S + ((size_t)b * T) * DS + flat);
    *reinterpret_cast<float4*>(&((float*)Sc)[flat]) = v;
  }

  // ---- one-time: s~(0) + zero tail (rt[528..543] must not be NaN) ----
  if (tid < 16) {
    rt[512 + tid] = (_Float16)S[((size_t)b * T) * DS + tid];
    rt[528 + tid] = (_Float16)0.0f;
  }

  // ---- one-time: W2 A-fragments (wave w: rows 64w+16mt+r15, k=32kt+8g+e) ----
  half8 w2f[4][4];
  #pragma unroll
  for (int mt = 0; mt < 4; ++mt)
    #pragma unroll
    for (int kt = 0; kt < 4; ++kt)
      w2f[mt][kt] = cvt8(W2 + ((size_t)b * DH + 64 * w + 16 * mt + r15) * DZ + 32 * kt + 8 * g);

  // ---- one-time: W1 A-fragments (rows 16mt+r15, k=64w+32kt+8g+e) ----
  half8 w1f[8][2];
  #pragma unroll
  for (int mt = 0; mt < 8; ++mt)
    #pragma unroll
    for (int kt = 0; kt < 2; ++kt)
      w1f[mt][kt] = cvt8(W1 + ((size_t)b * DZ + 16 * mt + r15) * DH + 64 * w + 32 * kt + 8 * g);

  // ---- one-time: per-wave tail fragment (C rows 16w+r15, k-lane 8g+e) ----
  half8 w1ft;
  #pragma unroll
  for (int e = 0; e < 8; ++e) w1ft[e] = (_Float16)0.0f;
  {
    const int row = 16 * w + r15;
    if (g == 0)      w1ft = cvt8(C + ((size_t)b * DZ + row) * DS + 0);
    else if (g == 1) w1ft = cvt8(C + ((size_t)b * DZ + row) * DS + 8);
  }

  // ---- one-time: h2 as acc-init (D rows 4g+j of each mt) ----
  f32x4 h2v[4];
  #pragma unroll
  for (int mt = 0; mt < 4; ++mt)
    h2v[mt] = *reinterpret_cast<const f32x4*>(h2 + (size_t)b * DH + 64 * w + 16 * mt + 4 * g);

  // ---- one-time: per-lane state constants (row0, duplicated x4) ----
  const float Areg  = A[(size_t)b * DZ + row0];
  const float h1reg = h1[(size_t)b * DZ + row0];
  float zfcur = 0.f;
  if (row0 < DX) {
    const float x0 = X[((size_t)b * T) * DX + row0];
    zfcur = (x0 != x0) ? 0.f : x0;     // zf(0) = TF(TF(0,X0,1), X0, 1/8) = x0
  }
  if (c4 == 0) zf_h[row0] = (_Float16)zfcur;
  __syncthreads();

  const f32x4 zero4 = {0.f, 0.f, 0.f, 0.f};

  for (int t = 0; t < T; ++t) {
    // ---- chunk boundary: flush out-chunk, stage next X/S chunk + s~ ----
    if ((t & (CHUNK - 1)) == 0 && t) {
      const int c0 = t - CHUNK;
      #pragma unroll
      for (int k = 0; k < 4; ++k) {
        const int flat = k * 2048 + tid * 4;
        const float4 v = *reinterpret_cast<const float4*>(&((float*)outc)[flat]);
        *reinterpret_cast<float4*>(out + ((size_t)b * T + c0) * DX + flat) = v;
      }
      #pragma unroll
      for (int k = 0; k < 4; ++k) {
        const int flat = k * 2048 + tid * 4;
        int srow = t + 1 + (flat >> 6);
        if (srow > T - 1) srow = T - 1;
        const float4 v = *reinterpret_cast<const float4*>(X + ((size_t)b * T + srow) * DX + (flat & 63));
        *reinterpret_cast<float4*>(&((float*)Xc)[flat]) = v;
      }
      {
        const int flat = tid * 4;
        const float4 v = *reinterpret_cast<const float4*>(S + ((size_t)b * T + t) * DS + flat);
        *reinterpret_cast<float4*>(&((float*)Sc)[flat]) = v;
      }
      if (tid < 16) rt[512 + tid] = (_Float16)S[((size_t)b * T + t) * DS + tid];
      __syncthreads();
    }
    const int tc = t & (CHUNK - 1);

    // ---- phase 1: pre = h2 + W2·zf (16 MFMA, 4 chains) ----
    half8 bz[4];
    #pragma unroll
    for (int kt = 0; kt < 4; ++kt)
      bz[kt] = *reinterpret_cast<const half8*>(zf_h + 32 * kt + 8 * g);

    f32x4 acc1[4];
    #pragma unroll
    for (int mt = 0; mt < 4; ++mt)
      acc1[mt] = __builtin_amdgcn_mfma_f32_16x16x32_f16(w2f[mt][0], bz[0], h2v[mt], 0, 0, 0);
    #pragma unroll
    for (int kt = 1; kt < 4; ++kt)
      #pragma unroll
      for (int mt = 0; mt < 4; ++mt)
        acc1[mt] = __builtin_amdgcn_mfma_f32_16x16x32_f16(w2f[mt][kt], bz[kt], acc1[mt], 0, 0, 0);

    // ---- bounce: column-spread single-op write of r[64w..64w+64) ----
    {
      const f32x4 s01 = sel4(r15 & 1, acc1[1], acc1[0]);
      const f32x4 s23 = sel4(r15 & 1, acc1[3], acc1[2]);
      const f32x4 sv  = sel4(r15 & 2, s23, s01);
      if (r15 < 4) {
        v4h p;
        p[0] = (_Float16)fmaxf(sv[0], 0.f);
        p[1] = (_Float16)fmaxf(sv[1], 0.f);
        p[2] = (_Float16)fmaxf(sv[2], 0.f);
        p[3] = (_Float16)fmaxf(sv[3], 0.f);
        *reinterpret_cast<v4h*>(&rt[64 * w + 16 * r15 + 4 * g]) = p;
      }
    }

    // ---- phase 2 (K-split): partials over k=[64w,64w+64), wave-local reads ----
    const half8 brt = *reinterpret_cast<const half8*>(rt + 512 + 8 * g);
    const half8 br0 = *reinterpret_cast<const half8*>(rt + 64 * w + 8 * g);
    const half8 br1 = *reinterpret_cast<const half8*>(rt + 64 * w + 32 + 8 * g);

    const f32x4 tailv = __builtin_amdgcn_mfma_f32_16x16x32_f16(w1ft, brt, zero4, 0, 0, 0);

    f32x4 acc2[8];
    #pragma unroll
    for (int mt = 0; mt < 8; ++mt)
      acc2[mt] = __builtin_amdgcn_mfma_f32_16x16x32_f16(w1f[mt][0], br0,
                                                        (mt == w) ? tailv : zero4, 0, 0, 0);
    #pragma unroll
    for (int mt = 0; mt < 8; ++mt)
      acc2[mt] = __builtin_amdgcn_mfma_f32_16x16x32_f16(w1f[mt][1], br1, acc2[mt], 0, 0, 0);

    // ---- pwrite: column-spread, every lane writes 2 f32 to part[z][w] ----
    {
      const int jp = r15 >> 3;         // 0/1 -> j-pair {0,1} / {2,3}
      float e0[8], e1[8];
      #pragma unroll
      for (int mt = 0; mt < 8; ++mt) {
        e0[mt] = jp ? acc2[mt][2] : acc2[mt][0];
        e1[mt] = jp ? acc2[mt][3] : acc2[mt][1];
      }
      const int m0 = r15 & 1, m1 = r15 & 2, m2 = r15 & 4;
      const float q0a = m0 ? e0[1] : e0[0], q0b = m0 ? e0[3] : e0[2];
      const float q0c = m0 ? e0[5] : e0[4], q0d = m0 ? e0[7] : e0[6];
      const float q1a = m0 ? e1[1] : e1[0], q1b = m0 ? e1[3] : e1[2];
      const float q1c = m0 ? e1[5] : e1[4], q1d = m0 ? e1[7] : e1[6];
      const float r0a = m1 ? q0b : q0a, r0b = m1 ? q0d : q0c;
      const float r1a = m1 ? q1b : q1a, r1b = m1 ? q1d : q1c;
      const float v0  = m2 ? r0b : r0a;
      const float v1  = m2 ? r1b : r1a;
      const int z0 = 16 * (r15 & 7) + 4 * g + 2 * jp;
      part[z0][w]     = v0;
      part[z0 + 1][w] = v1;
    }
    __syncthreads();   // B1: partials visible

    // ---- reduce: 2 reads + xor1/xor2 DPP -> u(row0) in every lane ----
    float u = part[row0][c4] + part[row0][4 + c4];
    u = dpp_xor_add<0xB1>(u);          // quad_perm(1,0,3,2): c4^1
    u = dpp_xor_add<0x4E>(u);          // quad_perm(2,3,0,1): c4^2

    // ---- update (per-lane f32 state, dup x4) ----
    const float zn = Areg * zfcur + u + h1reg;
    float zfn = zn;
    if (row0 < DX) {                   // wave-uniform branch (w<4)
      const float x = Xc[tc][row0];
      zfn = (x != x) ? zn : (0.125f * x + 0.875f * zn);
      if (c4 == 0) outc[tc][row0] = zn;
    }
    zfcur = zfn;
    if (c4 == 0) zf_h[row0] = (_Float16)zfn;

    // ---- stage s~(t+1) (wave 7; boundary restage handles the rest) ----
    if (w == 7 && l < 4 && ((t + 1) & (CHUNK - 1)) != 0) {
      const f32x4 sv = *reinterpret_cast<const f32x4*>(&Sc[(t + 1) & (CHUNK - 1)][4 * l]);
      v4h sp;
      #pragma unroll
      for (int j = 0; j < 4; ++j) sp[j] = (_Float16)sv[j];
      *reinterpret_cast<v4h*>(&rt[512 + 4 * l]) = sp;
    }
    __syncthreads();   // B2: zf(t+1) + s~(t+1) visible
  }

  // ---- final flush (last chunk) ----
  {
    const int c0 = T - CHUNK;
    #pragma unroll
    for (int k = 0; k < 4; ++k) {
      const int flat = k * 2048 + tid * 4;
      const float4 v = *reinterpret_cast<const float4*>(&((float*)outc)[flat]);
      *reinterpret_cast<float4*>(out + ((size_t)b * T + c0) * DX + flat) = v;
    }
  }
}

extern "C" void kernel_launch(void* const* d_in, const int* in_sizes, int n_in,
                              void* d_out, int out_size, void* d_ws, size_t ws_size,
                              hipStream_t stream) {
  const float* X  = (const float*)d_in[0];
  const float* S  = (const float*)d_in[1];
  const float* A  = (const float*)d_in[2];
  const float* W1 = (const float*)d_in[3];
  const float* W2 = (const float*)d_in[4];
  const float* h1 = (const float*)d_in[5];
  const float* h2 = (const float*)d_in[6];
  const float* C  = (const float*)d_in[7];
  float* out = (float*)d_out;
  plrnn_kernel<<<dim3(NB), dim3(512), 0, stream>>>(X, S, A, W1, W2, h1, h2, C, out);
}